// Round 11
// baseline (255.265 us; speedup 1.0000x reference)
//
#include <hip/hip_runtime.h>
#include <hip/hip_bf16.h>

#define B_ 4
#define C_ 512
#define T_ 1024
#define SCALE_ 0.125f
#define EPS_ 1e-5f

typedef unsigned short u16;
typedef __attribute__((ext_vector_type(8))) unsigned short u16x8;
typedef __attribute__((ext_vector_type(4))) unsigned short u16x4;
typedef __attribute__((ext_vector_type(8))) short s16x8;
typedef __attribute__((ext_vector_type(4))) float f32x4;
typedef __attribute__((ext_vector_type(4))) unsigned u32x4;

// ws byte offsets (ws is 256 MiB)
#define QT_OFF    (0x0ull)         // bf16 Qt[B][T][C]   4 MB (Q pre-scaled by 1/8)
#define KT_OFF    (0x400000ull)    // bf16 Kt[B][T][C]   4 MB
#define V_OFF     (0x800000ull)    // bf16 V [B][C][T]   4 MB
#define XT_OFF    (0xC00000ull)    // bf16 Xt[B][T][C]   4 MB
#define O_OFF     (0x1000000ull)   // bf16 O[B][8][T][64] 4 MB (normalized, pre-affine)
#define AB_OFF    (0x1410000ull)   // fp32 ab[B][8][2]
#define VSUM_OFF  (0x1420000ull)   // fp32 vsum[B][8][64]
#define BIAS2_OFF (0x1430000ull)   // fp32 bias2[B][8][512]
#define P_OFF     (0x2000000ull)   // bf16 P[B*8][1024][1024] 64 MB (unnormalized exp)
#define LP_OFF    (0x6000000ull)   // fp32 lpart [B*8][1024][32] 4 MB
#define L2P_OFF   (0x6400000ull)   // fp32 l2part[B*8][1024][32] 4 MB
#define LINV_OFF  (0x6800000ull)   // fp32 linv[B*8][1024] 128 KB

static __device__ __forceinline__ u16 f2bf(float f) {
  unsigned u = __float_as_uint(f);
  unsigned r = (u + 0x7fff + ((u >> 16) & 1)) >> 16;  // RNE
  return (u16)r;
}
static __device__ __forceinline__ unsigned pk2bf(float lo, float hi) {
  float2 f2v; f2v.x = lo; f2v.y = hi;
  __hip_bfloat162 h = __float22bfloat162_rn(f2v);  // v_cvt_pk_bf16_f32
  return *reinterpret_cast<unsigned*>(&h);
}
static __device__ __forceinline__ float b2f(u16 x) {
  return __uint_as_float(((unsigned)x) << 16);
}
static __device__ __forceinline__ f32x4 mfma16(s16x8 a, s16x8 b, f32x4 c) {
  return __builtin_amdgcn_mfma_f32_16x16x32_bf16(a, b, c, 0, 0, 0);
}

// ---------------- transpose x -> Xt[b][t][c] bf16 ----------------
__global__ __launch_bounds__(256) void transpose_x(const float* __restrict__ x,
                                                   u16* __restrict__ xt) {
  const int b = blockIdx.z;
  const int t0 = blockIdx.x << 6;
  const int c0 = blockIdx.y << 6;
  const float* __restrict__ X = x + (size_t)b * (C_ * (size_t)T_);
  u16* __restrict__ Xt = xt + (size_t)b * (T_ * (size_t)C_);
  __shared__ float Ts[64][65];
  const int tid = threadIdx.x;
#pragma unroll
  for (int i = 0; i < 4; ++i) {
    const int e = tid + (i << 8);
    const int r = e >> 4, c4 = e & 15;
    const float4 v = *(const float4*)(X + (size_t)(c0 + r) * T_ + t0 + (c4 << 2));
    Ts[r][(c4 << 2) + 0] = v.x; Ts[r][(c4 << 2) + 1] = v.y;
    Ts[r][(c4 << 2) + 2] = v.z; Ts[r][(c4 << 2) + 3] = v.w;
  }
  __syncthreads();
#pragma unroll
  for (int i = 0; i < 2; ++i) {
    const int e = tid + (i << 8);
    const int tt = e >> 3, c8 = e & 7;
    u16x8 o;
#pragma unroll
    for (int j = 0; j < 8; ++j) o[j] = f2bf(Ts[(c8 << 3) + j][tt]);
    *(u16x8*)(Xt + (size_t)(t0 + tt) * C_ + c0 + (c8 << 3)) = o;
  }
}

// ---- fused QKV projections: z = which*4 + b; which 0=Q 1=K (out [t][o]),
// ---- which 2=V (out [o][t]). 64x64 tiles.
__global__ __launch_bounds__(256) void gemm_qkv(const u16* __restrict__ xt,
                                                const float* __restrict__ wq,
                                                const float* __restrict__ wk,
                                                const float* __restrict__ wv,
                                                u16* __restrict__ qto,
                                                u16* __restrict__ kto,
                                                u16* __restrict__ vout) {
  const int which = blockIdx.z >> 2;
  const int b = blockIdx.z & 3;
  const u16* __restrict__ A = xt + (size_t)b * (T_ * (size_t)C_);
  __shared__ u16 As[64][72];
  __shared__ u16 Bs[64][72];
  const int tid = threadIdx.x;
  const int w = tid >> 6, lane = tid & 63, lr = lane & 15, lq = lane >> 4;
  const int mw = (w >> 1) << 5, nw = (w & 1) << 5;
  f32x4 acc[2][2] = {};

  if (which < 2) {
    const float* __restrict__ W = which ? wk : wq;
    u16* __restrict__ Y = (which ? kto : qto) + (size_t)b * (T_ * (size_t)C_);
    const float sc = which ? 1.0f : SCALE_;
    const int m0 = blockIdx.x << 6;  // t
    const int n0 = blockIdx.y << 6;  // o
    for (int k0 = 0; k0 < C_; k0 += 64) {
#pragma unroll
      for (int it = 0; it < 2; ++it) {
        const int e = tid + (it << 8);
        const int r = e >> 3, c8 = e & 7;
        *(u16x8*)&As[r][c8 << 3] =
            *(const u16x8*)(A + (size_t)(m0 + r) * C_ + k0 + (c8 << 3));
        const float* wr = W + (size_t)(n0 + r) * C_ + k0 + (c8 << 3);
        const float4 f0 = *(const float4*)wr;
        const float4 f1 = *(const float4*)(wr + 4);
        u16x8 o;
        o[0] = f2bf(f0.x); o[1] = f2bf(f0.y); o[2] = f2bf(f0.z); o[3] = f2bf(f0.w);
        o[4] = f2bf(f1.x); o[5] = f2bf(f1.y); o[6] = f2bf(f1.z); o[7] = f2bf(f1.w);
        *(u16x8*)&Bs[r][c8 << 3] = o;
      }
      __syncthreads();
#pragma unroll
      for (int kf = 0; kf < 2; ++kf) {
        const int ko = (kf << 5) + (lq << 3);
        s16x8 a[2], bb[2];
#pragma unroll
        for (int i = 0; i < 2; ++i)
          a[i] = *(const s16x8*)&As[mw + (i << 4) + lr][ko];
#pragma unroll
        for (int j = 0; j < 2; ++j)
          bb[j] = *(const s16x8*)&Bs[nw + (j << 4) + lr][ko];
#pragma unroll
        for (int i = 0; i < 2; ++i)
#pragma unroll
          for (int j = 0; j < 2; ++j) acc[i][j] = mfma16(a[i], bb[j], acc[i][j]);
      }
      __syncthreads();
    }
#pragma unroll
    for (int i = 0; i < 2; ++i) {
      const int row = mw + (i << 4) + (lq << 2);
#pragma unroll
      for (int j = 0; j < 2; ++j) {
        const int col = nw + (j << 4) + lr;
#pragma unroll
        for (int r = 0; r < 4; ++r)
          Y[(size_t)(m0 + row + r) * C_ + n0 + col] = f2bf(acc[i][j][r] * sc);
      }
    }
  } else {
    u16* __restrict__ Y = vout + (size_t)b * (C_ * (size_t)T_);
    const int n0 = blockIdx.x << 6;  // t
    const int m0 = blockIdx.y << 6;  // o
    for (int k0 = 0; k0 < C_; k0 += 64) {
#pragma unroll
      for (int it = 0; it < 2; ++it) {
        const int e = tid + (it << 8);
        const int r = e >> 3, c8 = e & 7;
        const float* wr = wv + (size_t)(m0 + r) * C_ + k0 + (c8 << 3);
        const float4 f0 = *(const float4*)wr;
        const float4 f1 = *(const float4*)(wr + 4);
        u16x8 o;
        o[0] = f2bf(f0.x); o[1] = f2bf(f0.y); o[2] = f2bf(f0.z); o[3] = f2bf(f0.w);
        o[4] = f2bf(f1.x); o[5] = f2bf(f1.y); o[6] = f2bf(f1.z); o[7] = f2bf(f1.w);
        *(u16x8*)&As[r][c8 << 3] = o;
        *(u16x8*)&Bs[r][c8 << 3] =
            *(const u16x8*)(A + (size_t)(n0 + r) * C_ + k0 + (c8 << 3));
      }
      __syncthreads();
#pragma unroll
      for (int kf = 0; kf < 2; ++kf) {
        const int ko = (kf << 5) + (lq << 3);
        s16x8 a[2], bb[2];
#pragma unroll
        for (int i = 0; i < 2; ++i)
          a[i] = *(const s16x8*)&As[mw + (i << 4) + lr][ko];
#pragma unroll
        for (int j = 0; j < 2; ++j)
          bb[j] = *(const s16x8*)&Bs[nw + (j << 4) + lr][ko];
#pragma unroll
        for (int i = 0; i < 2; ++i)
#pragma unroll
          for (int j = 0; j < 2; ++j) acc[i][j] = mfma16(a[i], bb[j], acc[i][j]);
      }
      __syncthreads();
    }
#pragma unroll
    for (int i = 0; i < 2; ++i) {
      const int row = mw + (i << 4) + (lq << 2);
#pragma unroll
      for (int j = 0; j < 2; ++j) {
        const int col = nw + (j << 4) + lr;
#pragma unroll
        for (int r = 0; r < 4; ++r)
          Y[(size_t)(m0 + row + r) * T_ + n0 + col] = f2bf(acc[i][j][r]);
      }
    }
  }
}

// ---------------- vsum[b][g][d] = sum_t V ----------------
__global__ __launch_bounds__(256) void vsum_k(const u16* __restrict__ v,
                                              float* __restrict__ vsum) {
  const int bg = blockIdx.x;  // b*8+g
  const int tid = threadIdx.x;
  const int d = tid >> 2, part = tid & 3;
  const u16* __restrict__ Vr =
      v + ((size_t)(bg >> 3) * C_ + ((bg & 7) << 6) + d) * T_ + (part << 8);
  float s = 0.f;
  for (int t = 0; t < 256; t += 8) {
    const u16x8 x = *(const u16x8*)(Vr + t);
#pragma unroll
    for (int j = 0; j < 8; ++j) s += b2f(x[j]);
  }
  s += __shfl_down(s, 2, 64);
  s += __shfl_down(s, 1, 64);
  if (part == 0) vsum[(bg << 6) + d] = s;
}

// ---- pass 1: S^T = K·Q^T (permuted K rows), head-mix, exp, P bf16 + l/l2 ---
// block (q16, t128, b); wave w covers t-chunk tb*128+w*32. Permuted A rows
// give each lane q=lr and t = chunk+quad*8+{0..7} contiguous -> one 16 B P
// store per g. launch_bounds(,6): 24 waves/CU to hide K-load latency.
__global__ __launch_bounds__(256, 6) void qk_mix(const u16* __restrict__ Qt,
                                                 const u16* __restrict__ Kt,
                                                 const float* __restrict__ wh,
                                                 u16* __restrict__ P,
                                                 float* __restrict__ lpart,
                                                 float* __restrict__ l2part) {
  const int qb = blockIdx.x;  // q /16
  const int tb = blockIdx.y;  // t /128
  const int b = blockIdx.z;
  const int tid = threadIdx.x;
  const int w = tid >> 6, lane = tid & 63;
  const int lr = lane & 15, quad = lane >> 4;
  const int q0 = qb << 4;
  const int bg0 = b << 3;

  __shared__ u16 Qs[16][522];

  {
    const u16* Qb = Qt + ((size_t)b * T_ + q0) * C_;
    for (int i = tid; i < 1024; i += 256) {
      const int r = i >> 6, c8 = i & 63;
      *(u16x8*)&Qs[r][c8 << 3] = *(const u16x8*)(Qb + (size_t)r * C_ + (c8 << 3));
    }
  }
  __syncthreads();

  const int tchunk = (tb << 7) + (w << 5);
  const int tp = ((lr >> 2) << 3) + (lr & 3);  // permuted row for a0; a1 = +4
  const u16* __restrict__ K0 =
      Kt + ((size_t)b * T_ + tchunk + tp) * C_ + (quad << 3);
  const u16* __restrict__ K1 = K0 + 4 * C_;
  const u16* __restrict__ Qrow = &Qs[lr][quad << 3];

  f32x4 m[8][2] = {};
#pragma unroll 2
  for (int h = 0; h < 8; ++h) {
    f32x4 a0 = {0.f, 0.f, 0.f, 0.f}, a1 = {0.f, 0.f, 0.f, 0.f};
#pragma unroll
    for (int kf = 0; kf < 2; ++kf) {
      const int co = (h << 6) + (kf << 5);
      const s16x8 qf = *(const s16x8*)(Qrow + co);
      const s16x8 k0 = *(const s16x8*)(K0 + co);
      const s16x8 k1 = *(const s16x8*)(K1 + co);
      a0 = mfma16(k0, qf, a0);
      a1 = mfma16(k1, qf, a1);
    }
#pragma unroll
    for (int g = 0; g < 8; ++g) {
      const float wgh = wh[(g << 3) + h];  // uniform -> SGPR
      m[g][0] += a0 * wgh;
      m[g][1] += a1 * wgh;
    }
  }
  // lane's t slots: m[g][0] -> tchunk+quad*8+{0..3}, m[g][1] -> +{4..7}; q=q0+lr
  const size_t pq = ((size_t)q0 + lr) * 1024 + tchunk + (quad << 3);
#pragma unroll
  for (int g = 0; g < 8; ++g) {
    f32x4 e0, e1;
#pragma unroll
    for (int k = 0; k < 4; ++k) {
      e0[k] = __expf(m[g][0][k]);
      e1[k] = __expf(m[g][1][k]);
    }
    u32x4 o;
    o[0] = pk2bf(e0[0], e0[1]);
    o[1] = pk2bf(e0[2], e0[3]);
    o[2] = pk2bf(e1[0], e1[1]);
    o[3] = pk2bf(e1[2], e1[3]);
    *(u32x4*)(P + (((size_t)(bg0 + g)) << 20) + pq) = o;
    float l = e0[0] + e0[1] + e0[2] + e0[3] + e1[0] + e1[1] + e1[2] + e1[3];
    float l2 = e0[0] * e0[0] + e0[1] * e0[1] + e0[2] * e0[2] + e0[3] * e0[3] +
               e1[0] * e1[0] + e1[1] * e1[1] + e1[2] * e1[2] + e1[3] * e1[3];
    l += __shfl_xor(l, 16, 64);
    l += __shfl_xor(l, 32, 64);
    l2 += __shfl_xor(l2, 16, 64);
    l2 += __shfl_xor(l2, 32, 64);
    if (quad == 0) {
      const size_t idx =
          ((((size_t)(bg0 + g)) << 10) + q0 + lr) * 32 + (tb << 2) + w;
      lpart[idx] = l;
      l2part[idx] = l2;
    }
  }
}

// ---- reduce l partials: linv[bg][q], and alpha/beta' per (b,g) -> ab ----
__global__ __launch_bounds__(256) void reduce_l(const float* __restrict__ lpart,
                                                const float* __restrict__ l2part,
                                                const float* __restrict__ gamma,
                                                const float* __restrict__ beta,
                                                float* __restrict__ linv,
                                                float* __restrict__ ab) {
  const int bg = blockIdx.x;
  const int g = bg & 7;
  const int tid = threadIdx.x;
  float ssq = 0.f;
#pragma unroll
  for (int k = 0; k < 4; ++k) {
    const int q = (tid << 2) + k;
    const float* lp = lpart + (((size_t)bg << 10) + q) * 32;
    const float* l2p = l2part + (((size_t)bg << 10) + q) * 32;
    float l = 0.f, l2 = 0.f;
#pragma unroll
    for (int j = 0; j < 32; j += 4) {
      const f32x4 a = *(const f32x4*)(lp + j);
      const f32x4 c = *(const f32x4*)(l2p + j);
      l += a[0] + a[1] + a[2] + a[3];
      l2 += c[0] + c[1] + c[2] + c[3];
    }
    linv[((size_t)bg << 10) + q] = 1.f / l;
    ssq += l2 / (l * l);
  }
#pragma unroll
  for (int off = 32; off; off >>= 1) ssq += __shfl_xor(ssq, off, 64);
  __shared__ float red[4];
  if ((tid & 63) == 0) red[tid >> 6] = ssq;
  __syncthreads();
  if (tid == 0) {
    const float s = red[0] + red[1] + red[2] + red[3];
    const float mean = 0.0009765625f;
    const float var = s * (1.f / 1048576.f) - mean * mean;
    const float al = gamma[g] * rsqrtf(var + EPS_);
    ab[bg * 2] = al;
    ab[bg * 2 + 1] = beta[g] - al * mean;
  }
}

// ---- pass 2: O[bg][q][d] = (P[q][:] @ V[d][:]^T) * linv[q], BK=64 ----
__global__ __launch_bounds__(256) void gemm_pv(const u16* __restrict__ P,
                                               const u16* __restrict__ v,
                                               const float* __restrict__ linv,
                                               u16* __restrict__ O) {
  const int qt0 = blockIdx.x << 6;
  const int bg = blockIdx.y;
  const u16* __restrict__ A = P + (((size_t)bg << 10) + qt0) * 1024;
  const u16* __restrict__ Vg =
      v + ((size_t)(bg >> 3) * C_ + ((bg & 7) << 6)) * 1024;
  __shared__ u16 Ps[64][72];
  __shared__ u16 Vs[64][72];
  __shared__ float lT[64];
  const int tid = threadIdx.x;
  const int w = tid >> 6, lane = tid & 63, lr = lane & 15, quad = lane >> 4;
  if (tid < 64) lT[tid] = linv[((size_t)bg << 10) + qt0 + tid];
  f32x4 acc[4] = {};
  const int r = tid >> 2, c4 = tid & 3;
#pragma unroll 1
  for (int k0 = 0; k0 < 1024; k0 += 64) {
    __syncthreads();
    *(u16x8*)&Ps[r][c4 << 3] =
        *(const u16x8*)(A + (size_t)r * 1024 + k0 + (c4 << 3));
    *(u16x8*)&Ps[r][32 + (c4 << 3)] =
        *(const u16x8*)(A + (size_t)r * 1024 + k0 + 32 + (c4 << 3));
    *(u16x8*)&Vs[r][c4 << 3] =
        *(const u16x8*)(Vg + (size_t)r * 1024 + k0 + (c4 << 3));
    *(u16x8*)&Vs[r][32 + (c4 << 3)] =
        *(const u16x8*)(Vg + (size_t)r * 1024 + k0 + 32 + (c4 << 3));
    __syncthreads();
#pragma unroll
    for (int kf = 0; kf < 2; ++kf) {
      const int ko = (kf << 5) + (quad << 3);
      const s16x8 a = *(const s16x8*)&Ps[(w << 4) + lr][ko];
#pragma unroll
      for (int j = 0; j < 4; ++j) {
        const s16x8 bb = *(const s16x8*)&Vs[(j << 4) + lr][ko];
        acc[j] = mfma16(a, bb, acc[j]);
      }
    }
  }
#pragma unroll
  for (int j = 0; j < 4; ++j) {
    const int d = (j << 4) + lr;
#pragma unroll
    for (int rr = 0; rr < 4; ++rr) {
      const int q = (w << 4) + (quad << 2) + rr;
      O[(((size_t)bg << 10) + qt0 + q) * 64 + d] = f2bf(acc[j][rr] * lT[q]);
    }
  }
}

// -------- bias2[b][g][o] = bp[o] + bt2[b,g] * sum_d vsum[b,g,d]*wsum[o][d]
__global__ __launch_bounds__(256) void bias2_k(const float* __restrict__ wp,
                                               const float* __restrict__ bp,
                                               const float* __restrict__ ab,
                                               const float* __restrict__ vsum,
                                               float* __restrict__ bias2) {
  const int idx = (blockIdx.x << 8) + threadIdx.x;  // 16384 = B*8*512
  const int b = idx >> 12, g = (idx >> 9) & 7, o = idx & 511;
  const float bt2 = ab[(((b << 3) + g) << 1) + 1];
  const float* wr = wp + (size_t)o * C_;
  const float* vs = vsum + (((b << 3) + g) << 6);
  float acc = 0.f;
#pragma unroll
  for (int d = 0; d < 64; d += 4) {
    const float4 vv4 = *(const float4*)(vs + d);
    float4 ws4 = {0.f, 0.f, 0.f, 0.f};
#pragma unroll
    for (int j = 0; j < 8; ++j) {
      const float4 wv4 = *(const float4*)(wr + (j << 6) + d);
      ws4.x += wv4.x; ws4.y += wv4.y; ws4.z += wv4.z; ws4.w += wv4.w;
    }
    acc += ws4.x * vv4.x + ws4.y * vv4.y + ws4.z * vv4.z + ws4.w * vv4.w;
  }
  bias2[(((b << 3) + g) << 9) + o] = bp[o] + bt2 * acc;
}

// ------- y = al[b,g(t)]*(Mnorm @ Wp^T) + bias2[b][g(t)][o], 64x64 tiles ----
__global__ __launch_bounds__(256) void gemm_proj(const u16* __restrict__ O,
                                                 const float* __restrict__ wp,
                                                 const float* __restrict__ ab,
                                                 const float* __restrict__ bias2,
                                                 float* __restrict__ y) {
  const int b = blockIdx.z;
  const int m0 = blockIdx.y << 6;  // o
  const int n0 = blockIdx.x << 6;  // t
  const int gidx = blockIdx.x >> 1;
  const u16* __restrict__ Ob = O + (size_t)b * (8 * T_ * 64);
  __shared__ u16 As[64][72];
  __shared__ u16 Bs[64][72];
  const int tid = threadIdx.x;
  const int w = tid >> 6, lane = tid & 63, lr = lane & 15, lq = lane >> 4;
  const int mw = (w >> 1) << 5, nw = (w & 1) << 5;
  f32x4 acc[2][2] = {};
  for (int k0 = 0; k0 < C_; k0 += 64) {
#pragma unroll
    for (int it = 0; it < 2; ++it) {
      const int e = tid + (it << 8);
      const int r = e >> 3, c8 = e & 7;
      const float* wr = wp + (size_t)(m0 + r) * C_ + k0 + (c8 << 3);
      const float4 f0 = *(const float4*)wr;
      const float4 f1 = *(const float4*)(wr + 4);
      u16x8 o;
      o[0] = f2bf(f0.x); o[1] = f2bf(f0.y); o[2] = f2bf(f0.z); o[3] = f2bf(f0.w);
      o[4] = f2bf(f1.x); o[5] = f2bf(f1.y); o[6] = f2bf(f1.z); o[7] = f2bf(f1.w);
      *(u16x8*)&As[r][c8 << 3] = o;
      const int t = n0 + r;
      const int c = k0 + (c8 << 3);
      *(u16x8*)&Bs[r][c8 << 3] =
          *(const u16x8*)(Ob + (size_t)(t >> 7) * (T_ * 64) +
                          (size_t)(((t & 127) << 3) + (c >> 6)) * 64 + (c & 63));
    }
    __syncthreads();
#pragma unroll
    for (int kf = 0; kf < 2; ++kf) {
      const int ko = (kf << 5) + (lq << 3);
      s16x8 a[2], bb[2];
#pragma unroll
      for (int i = 0; i < 2; ++i) a[i] = *(const s16x8*)&As[mw + (i << 4) + lr][ko];
#pragma unroll
      for (int j = 0; j < 2; ++j) bb[j] = *(const s16x8*)&Bs[nw + (j << 4) + lr][ko];
#pragma unroll
      for (int i = 0; i < 2; ++i)
#pragma unroll
        for (int j = 0; j < 2; ++j) acc[i][j] = mfma16(a[i], bb[j], acc[i][j]);
    }
    __syncthreads();
  }
  const float al = ab[(((b << 3) + gidx) << 1)];
  const float* __restrict__ b2 = bias2 + (((b << 3) + gidx) << 9);
#pragma unroll
  for (int i = 0; i < 2; ++i) {
    const int row = mw + (i << 4) + (lq << 2);
#pragma unroll
    for (int j = 0; j < 2; ++j) {
      const int col = nw + (j << 4) + lr;
#pragma unroll
      for (int r = 0; r < 4; ++r)
        y[(size_t)b * (C_ * (size_t)T_) + (size_t)(m0 + row + r) * T_ + n0 + col] =
            acc[i][j][r] * al + b2[m0 + row + r];
    }
  }
}

extern "C" void kernel_launch(void* const* d_in, const int* in_sizes, int n_in,
                              void* d_out, int out_size, void* d_ws,
                              size_t ws_size, hipStream_t stream) {
  const float* x = (const float*)d_in[0];
  const float* wq = (const float*)d_in[1];
  const float* wk = (const float*)d_in[2];
  const float* wv = (const float*)d_in[3];
  const float* wh = (const float*)d_in[4];
  const float* gm = (const float*)d_in[5];
  const float* bt = (const float*)d_in[6];
  const float* wp = (const float*)d_in[7];
  const float* bp = (const float*)d_in[8];
  float* y = (float*)d_out;
  char* wsb = (char*)d_ws;

  u16* Qt = (u16*)(wsb + QT_OFF);
  u16* Kt = (u16*)(wsb + KT_OFF);
  u16* V = (u16*)(wsb + V_OFF);
  u16* Xt = (u16*)(wsb + XT_OFF);
  u16* Og = (u16*)(wsb + O_OFF);
  float* ab = (float*)(wsb + AB_OFF);
  float* vsum = (float*)(wsb + VSUM_OFF);
  float* bias2 = (float*)(wsb + BIAS2_OFF);
  u16* P = (u16*)(wsb + P_OFF);
  float* lpart = (float*)(wsb + LP_OFF);
  float* l2part = (float*)(wsb + L2P_OFF);
  float* linv = (float*)(wsb + LINV_OFF);

  transpose_x<<<dim3(16, 8, 4), 256, 0, stream>>>(x, Xt);
  gemm_qkv<<<dim3(16, 8, 12), 256, 0, stream>>>(Xt, wq, wk, wv, Qt, Kt, V);
  vsum_k<<<dim3(32), 256, 0, stream>>>(V, vsum);
  qk_mix<<<dim3(64, 8, 4), 256, 0, stream>>>(Qt, Kt, wh, P, lpart, l2part);
  reduce_l<<<dim3(32), 256, 0, stream>>>(lpart, l2part, gm, bt, linv, ab);
  gemm_pv<<<dim3(16, 32), 256, 0, stream>>>(P, V, linv, Og);
  bias2_k<<<dim3(64), 256, 0, stream>>>(wp, bp, ab, vsum, bias2);
  gemm_proj<<<dim3(16, 8, 4), 256, 0, stream>>>(Og, wp, ab, bias2, y);
}

// Round 12
// 208.911 us; speedup vs baseline: 1.2219x; 1.2219x over previous
//
#include <hip/hip_runtime.h>
#include <hip/hip_bf16.h>

#define B_ 4
#define C_ 512
#define T_ 1024
#define SCALE_ 0.125f
#define EPS_ 1e-5f

typedef unsigned short u16;
typedef __attribute__((ext_vector_type(8))) unsigned short u16x8;
typedef __attribute__((ext_vector_type(4))) unsigned short u16x4;
typedef __attribute__((ext_vector_type(8))) short s16x8;
typedef __attribute__((ext_vector_type(4))) float f32x4;
typedef __attribute__((ext_vector_type(4))) unsigned u32x4;

// ws byte offsets (ws is 256 MiB)
#define QT_OFF    (0x0ull)         // bf16 Qt[B][T][C]   4 MB (Q pre-scaled by 1/8)
#define KT_OFF    (0x400000ull)    // bf16 Kt[B][T][C]   4 MB
#define V_OFF     (0x800000ull)    // bf16 V [B][C][T]   4 MB
#define XT_OFF    (0xC00000ull)    // bf16 Xt[B][T][C]   4 MB
#define O_OFF     (0x1000000ull)   // bf16 O[B][8][T][64] 4 MB (normalized, pre-affine)
#define AB_OFF    (0x1410000ull)   // fp32 ab[B][8][2]
#define VSUM_OFF  (0x1420000ull)   // fp32 vsum[B][8][64]
#define BIAS2_OFF (0x1430000ull)   // fp32 bias2[B][8][512]
#define P_OFF     (0x2000000ull)   // bf16 P[B*8][1024][1024] 64 MB (unnormalized exp)
#define LP_OFF    (0x6000000ull)   // fp32 lpart [B*8][1024][32] 4 MB
#define L2P_OFF   (0x6400000ull)   // fp32 l2part[B*8][1024][32] 4 MB
#define LINV_OFF  (0x6800000ull)   // fp32 linv[B*8][1024] 128 KB

static __device__ __forceinline__ u16 f2bf(float f) {
  unsigned u = __float_as_uint(f);
  unsigned r = (u + 0x7fff + ((u >> 16) & 1)) >> 16;  // RNE
  return (u16)r;
}
static __device__ __forceinline__ unsigned pk2bf(float lo, float hi) {
  float2 f2v; f2v.x = lo; f2v.y = hi;
  __hip_bfloat162 h = __float22bfloat162_rn(f2v);  // v_cvt_pk_bf16_f32
  return *reinterpret_cast<unsigned*>(&h);
}
static __device__ __forceinline__ float b2f(u16 x) {
  return __uint_as_float(((unsigned)x) << 16);
}
static __device__ __forceinline__ f32x4 mfma16(s16x8 a, s16x8 b, f32x4 c) {
  return __builtin_amdgcn_mfma_f32_16x16x32_bf16(a, b, c, 0, 0, 0);
}

// ---------------- transpose x -> Xt[b][t][c] bf16 ----------------
__global__ __launch_bounds__(256) void transpose_x(const float* __restrict__ x,
                                                   u16* __restrict__ xt) {
  const int b = blockIdx.z;
  const int t0 = blockIdx.x << 6;
  const int c0 = blockIdx.y << 6;
  const float* __restrict__ X = x + (size_t)b * (C_ * (size_t)T_);
  u16* __restrict__ Xt = xt + (size_t)b * (T_ * (size_t)C_);
  __shared__ float Ts[64][65];
  const int tid = threadIdx.x;
#pragma unroll
  for (int i = 0; i < 4; ++i) {
    const int e = tid + (i << 8);
    const int r = e >> 4, c4 = e & 15;
    const float4 v = *(const float4*)(X + (size_t)(c0 + r) * T_ + t0 + (c4 << 2));
    Ts[r][(c4 << 2) + 0] = v.x; Ts[r][(c4 << 2) + 1] = v.y;
    Ts[r][(c4 << 2) + 2] = v.z; Ts[r][(c4 << 2) + 3] = v.w;
  }
  __syncthreads();
#pragma unroll
  for (int i = 0; i < 2; ++i) {
    const int e = tid + (i << 8);
    const int tt = e >> 3, c8 = e & 7;
    u16x8 o;
#pragma unroll
    for (int j = 0; j < 8; ++j) o[j] = f2bf(Ts[(c8 << 3) + j][tt]);
    *(u16x8*)(Xt + (size_t)(t0 + tt) * C_ + c0 + (c8 << 3)) = o;
  }
}

// ---- fused QKV projections: z = which*4 + b; which 0=Q 1=K (out [t][o]),
// ---- which 2=V (out [o][t]). 64x64 tiles.
__global__ __launch_bounds__(256) void gemm_qkv(const u16* __restrict__ xt,
                                                const float* __restrict__ wq,
                                                const float* __restrict__ wk,
                                                const float* __restrict__ wv,
                                                u16* __restrict__ qto,
                                                u16* __restrict__ kto,
                                                u16* __restrict__ vout) {
  const int which = blockIdx.z >> 2;
  const int b = blockIdx.z & 3;
  const u16* __restrict__ A = xt + (size_t)b * (T_ * (size_t)C_);
  __shared__ u16 As[64][72];
  __shared__ u16 Bs[64][72];
  const int tid = threadIdx.x;
  const int w = tid >> 6, lane = tid & 63, lr = lane & 15, lq = lane >> 4;
  const int mw = (w >> 1) << 5, nw = (w & 1) << 5;
  f32x4 acc[2][2] = {};

  if (which < 2) {
    const float* __restrict__ W = which ? wk : wq;
    u16* __restrict__ Y = (which ? kto : qto) + (size_t)b * (T_ * (size_t)C_);
    const float sc = which ? 1.0f : SCALE_;
    const int m0 = blockIdx.x << 6;  // t
    const int n0 = blockIdx.y << 6;  // o
    for (int k0 = 0; k0 < C_; k0 += 64) {
#pragma unroll
      for (int it = 0; it < 2; ++it) {
        const int e = tid + (it << 8);
        const int r = e >> 3, c8 = e & 7;
        *(u16x8*)&As[r][c8 << 3] =
            *(const u16x8*)(A + (size_t)(m0 + r) * C_ + k0 + (c8 << 3));
        const float* wr = W + (size_t)(n0 + r) * C_ + k0 + (c8 << 3);
        const float4 f0 = *(const float4*)wr;
        const float4 f1 = *(const float4*)(wr + 4);
        u16x8 o;
        o[0] = f2bf(f0.x); o[1] = f2bf(f0.y); o[2] = f2bf(f0.z); o[3] = f2bf(f0.w);
        o[4] = f2bf(f1.x); o[5] = f2bf(f1.y); o[6] = f2bf(f1.z); o[7] = f2bf(f1.w);
        *(u16x8*)&Bs[r][c8 << 3] = o;
      }
      __syncthreads();
#pragma unroll
      for (int kf = 0; kf < 2; ++kf) {
        const int ko = (kf << 5) + (lq << 3);
        s16x8 a[2], bb[2];
#pragma unroll
        for (int i = 0; i < 2; ++i)
          a[i] = *(const s16x8*)&As[mw + (i << 4) + lr][ko];
#pragma unroll
        for (int j = 0; j < 2; ++j)
          bb[j] = *(const s16x8*)&Bs[nw + (j << 4) + lr][ko];
#pragma unroll
        for (int i = 0; i < 2; ++i)
#pragma unroll
          for (int j = 0; j < 2; ++j) acc[i][j] = mfma16(a[i], bb[j], acc[i][j]);
      }
      __syncthreads();
    }
#pragma unroll
    for (int i = 0; i < 2; ++i) {
      const int row = mw + (i << 4) + (lq << 2);
#pragma unroll
      for (int j = 0; j < 2; ++j) {
        const int col = nw + (j << 4) + lr;
#pragma unroll
        for (int r = 0; r < 4; ++r)
          Y[(size_t)(m0 + row + r) * C_ + n0 + col] = f2bf(acc[i][j][r] * sc);
      }
    }
  } else {
    u16* __restrict__ Y = vout + (size_t)b * (C_ * (size_t)T_);
    const int n0 = blockIdx.x << 6;  // t
    const int m0 = blockIdx.y << 6;  // o
    for (int k0 = 0; k0 < C_; k0 += 64) {
#pragma unroll
      for (int it = 0; it < 2; ++it) {
        const int e = tid + (it << 8);
        const int r = e >> 3, c8 = e & 7;
        const float* wr = wv + (size_t)(m0 + r) * C_ + k0 + (c8 << 3);
        const float4 f0 = *(const float4*)wr;
        const float4 f1 = *(const float4*)(wr + 4);
        u16x8 o;
        o[0] = f2bf(f0.x); o[1] = f2bf(f0.y); o[2] = f2bf(f0.z); o[3] = f2bf(f0.w);
        o[4] = f2bf(f1.x); o[5] = f2bf(f1.y); o[6] = f2bf(f1.z); o[7] = f2bf(f1.w);
        *(u16x8*)&As[r][c8 << 3] = o;
        *(u16x8*)&Bs[r][c8 << 3] =
            *(const u16x8*)(A + (size_t)(n0 + r) * C_ + k0 + (c8 << 3));
      }
      __syncthreads();
#pragma unroll
      for (int kf = 0; kf < 2; ++kf) {
        const int ko = (kf << 5) + (lq << 3);
        s16x8 a[2], bb[2];
#pragma unroll
        for (int i = 0; i < 2; ++i)
          a[i] = *(const s16x8*)&As[mw + (i << 4) + lr][ko];
#pragma unroll
        for (int j = 0; j < 2; ++j)
          bb[j] = *(const s16x8*)&Bs[nw + (j << 4) + lr][ko];
#pragma unroll
        for (int i = 0; i < 2; ++i)
#pragma unroll
          for (int j = 0; j < 2; ++j) acc[i][j] = mfma16(a[i], bb[j], acc[i][j]);
      }
      __syncthreads();
    }
#pragma unroll
    for (int i = 0; i < 2; ++i) {
      const int row = mw + (i << 4) + (lq << 2);
#pragma unroll
      for (int j = 0; j < 2; ++j) {
        const int col = nw + (j << 4) + lr;
#pragma unroll
        for (int r = 0; r < 4; ++r)
          Y[(size_t)(m0 + row + r) * T_ + n0 + col] = f2bf(acc[i][j][r]);
      }
    }
  }
}

// ---------------- vsum[b][g][d] = sum_t V ----------------
__global__ __launch_bounds__(256) void vsum_k(const u16* __restrict__ v,
                                              float* __restrict__ vsum) {
  const int bg = blockIdx.x;  // b*8+g
  const int tid = threadIdx.x;
  const int d = tid >> 2, part = tid & 3;
  const u16* __restrict__ Vr =
      v + ((size_t)(bg >> 3) * C_ + ((bg & 7) << 6) + d) * T_ + (part << 8);
  float s = 0.f;
  for (int t = 0; t < 256; t += 8) {
    const u16x8 x = *(const u16x8*)(Vr + t);
#pragma unroll
    for (int j = 0; j < 8; ++j) s += b2f(x[j]);
  }
  s += __shfl_down(s, 2, 64);
  s += __shfl_down(s, 1, 64);
  if (part == 0) vsum[(bg << 6) + d] = s;
}

// ---- pass 1: S^T = K·Q^T (permuted K rows), head-mix, exp, P bf16 + l/l2 ---
// block (q16, t128, b); wave w covers t-chunk tb*128+w*32. Permuted A rows
// give each lane q=lr and t = chunk+quad*8+{0..7} contiguous -> one 16 B P
// store per g. launch_bounds(256,4): proven no-spill config (VGPR 64).
__global__ __launch_bounds__(256, 4) void qk_mix(const u16* __restrict__ Qt,
                                                 const u16* __restrict__ Kt,
                                                 const float* __restrict__ wh,
                                                 u16* __restrict__ P,
                                                 float* __restrict__ lpart,
                                                 float* __restrict__ l2part) {
  const int qb = blockIdx.x;  // q /16
  const int tb = blockIdx.y;  // t /128
  const int b = blockIdx.z;
  const int tid = threadIdx.x;
  const int w = tid >> 6, lane = tid & 63;
  const int lr = lane & 15, quad = lane >> 4;
  const int q0 = qb << 4;
  const int bg0 = b << 3;

  __shared__ u16 Qs[16][522];

  {
    const u16* Qb = Qt + ((size_t)b * T_ + q0) * C_;
    for (int i = tid; i < 1024; i += 256) {
      const int r = i >> 6, c8 = i & 63;
      *(u16x8*)&Qs[r][c8 << 3] = *(const u16x8*)(Qb + (size_t)r * C_ + (c8 << 3));
    }
  }
  __syncthreads();

  const int tchunk = (tb << 7) + (w << 5);
  const int tp = ((lr >> 2) << 3) + (lr & 3);  // permuted row for a0; a1 = +4
  const u16* __restrict__ K0 =
      Kt + ((size_t)b * T_ + tchunk + tp) * C_ + (quad << 3);
  const u16* __restrict__ K1 = K0 + 4 * C_;
  const u16* __restrict__ Qrow = &Qs[lr][quad << 3];

  f32x4 m[8][2] = {};
#pragma unroll 2
  for (int h = 0; h < 8; ++h) {
    f32x4 a0 = {0.f, 0.f, 0.f, 0.f}, a1 = {0.f, 0.f, 0.f, 0.f};
#pragma unroll
    for (int kf = 0; kf < 2; ++kf) {
      const int co = (h << 6) + (kf << 5);
      const s16x8 qf = *(const s16x8*)(Qrow + co);
      const s16x8 k0 = *(const s16x8*)(K0 + co);
      const s16x8 k1 = *(const s16x8*)(K1 + co);
      a0 = mfma16(k0, qf, a0);
      a1 = mfma16(k1, qf, a1);
    }
#pragma unroll
    for (int g = 0; g < 8; ++g) {
      const float wgh = wh[(g << 3) + h];  // uniform -> SGPR
      m[g][0] += a0 * wgh;
      m[g][1] += a1 * wgh;
    }
  }
  // lane's t slots: m[g][0] -> tchunk+quad*8+{0..3}, m[g][1] -> +{4..7}; q=q0+lr
  const size_t pq = ((size_t)q0 + lr) * 1024 + tchunk + (quad << 3);
#pragma unroll
  for (int g = 0; g < 8; ++g) {
    f32x4 e0, e1;
#pragma unroll
    for (int k = 0; k < 4; ++k) {
      e0[k] = __expf(m[g][0][k]);
      e1[k] = __expf(m[g][1][k]);
    }
    u32x4 o;
    o[0] = pk2bf(e0[0], e0[1]);
    o[1] = pk2bf(e0[2], e0[3]);
    o[2] = pk2bf(e1[0], e1[1]);
    o[3] = pk2bf(e1[2], e1[3]);
    *(u32x4*)(P + (((size_t)(bg0 + g)) << 20) + pq) = o;
    float l = e0[0] + e0[1] + e0[2] + e0[3] + e1[0] + e1[1] + e1[2] + e1[3];
    float l2 = e0[0] * e0[0] + e0[1] * e0[1] + e0[2] * e0[2] + e0[3] * e0[3] +
               e1[0] * e1[0] + e1[1] * e1[1] + e1[2] * e1[2] + e1[3] * e1[3];
    l += __shfl_xor(l, 16, 64);
    l += __shfl_xor(l, 32, 64);
    l2 += __shfl_xor(l2, 16, 64);
    l2 += __shfl_xor(l2, 32, 64);
    if (quad == 0) {
      const size_t idx =
          ((((size_t)(bg0 + g)) << 10) + q0 + lr) * 32 + (tb << 2) + w;
      lpart[idx] = l;
      l2part[idx] = l2;
    }
  }
}

// ---- reduce l partials: linv[bg][q], and alpha/beta' per (b,g) -> ab ----
__global__ __launch_bounds__(256) void reduce_l(const float* __restrict__ lpart,
                                                const float* __restrict__ l2part,
                                                const float* __restrict__ gamma,
                                                const float* __restrict__ beta,
                                                float* __restrict__ linv,
                                                float* __restrict__ ab) {
  const int bg = blockIdx.x;
  const int g = bg & 7;
  const int tid = threadIdx.x;
  float ssq = 0.f;
#pragma unroll
  for (int k = 0; k < 4; ++k) {
    const int q = (tid << 2) + k;
    const float* lp = lpart + (((size_t)bg << 10) + q) * 32;
    const float* l2p = l2part + (((size_t)bg << 10) + q) * 32;
    float l = 0.f, l2 = 0.f;
#pragma unroll
    for (int j = 0; j < 32; j += 4) {
      const f32x4 a = *(const f32x4*)(lp + j);
      const f32x4 c = *(const f32x4*)(l2p + j);
      l += a[0] + a[1] + a[2] + a[3];
      l2 += c[0] + c[1] + c[2] + c[3];
    }
    linv[((size_t)bg << 10) + q] = 1.f / l;
    ssq += l2 / (l * l);
  }
#pragma unroll
  for (int off = 32; off; off >>= 1) ssq += __shfl_xor(ssq, off, 64);
  __shared__ float red[4];
  if ((tid & 63) == 0) red[tid >> 6] = ssq;
  __syncthreads();
  if (tid == 0) {
    const float s = red[0] + red[1] + red[2] + red[3];
    const float mean = 0.0009765625f;
    const float var = s * (1.f / 1048576.f) - mean * mean;
    const float al = gamma[g] * rsqrtf(var + EPS_);
    ab[bg * 2] = al;
    ab[bg * 2 + 1] = beta[g] - al * mean;
  }
}

// ---- pass 2: O[bg][q][d] = (P[q][:] @ V[d][:]^T) * linv[q], BK=64 ----
__global__ __launch_bounds__(256) void gemm_pv(const u16* __restrict__ P,
                                               const u16* __restrict__ v,
                                               const float* __restrict__ linv,
                                               u16* __restrict__ O) {
  const int qt0 = blockIdx.x << 6;
  const int bg = blockIdx.y;
  const u16* __restrict__ A = P + (((size_t)bg << 10) + qt0) * 1024;
  const u16* __restrict__ Vg =
      v + ((size_t)(bg >> 3) * C_ + ((bg & 7) << 6)) * 1024;
  __shared__ u16 Ps[64][72];
  __shared__ u16 Vs[64][72];
  __shared__ float lT[64];
  const int tid = threadIdx.x;
  const int w = tid >> 6, lane = tid & 63, lr = lane & 15, quad = lane >> 4;
  if (tid < 64) lT[tid] = linv[((size_t)bg << 10) + qt0 + tid];
  f32x4 acc[4] = {};
  const int r = tid >> 2, c4 = tid & 3;
#pragma unroll 1
  for (int k0 = 0; k0 < 1024; k0 += 64) {
    __syncthreads();
    *(u16x8*)&Ps[r][c4 << 3] =
        *(const u16x8*)(A + (size_t)r * 1024 + k0 + (c4 << 3));
    *(u16x8*)&Ps[r][32 + (c4 << 3)] =
        *(const u16x8*)(A + (size_t)r * 1024 + k0 + 32 + (c4 << 3));
    *(u16x8*)&Vs[r][c4 << 3] =
        *(const u16x8*)(Vg + (size_t)r * 1024 + k0 + (c4 << 3));
    *(u16x8*)&Vs[r][32 + (c4 << 3)] =
        *(const u16x8*)(Vg + (size_t)r * 1024 + k0 + 32 + (c4 << 3));
    __syncthreads();
#pragma unroll
    for (int kf = 0; kf < 2; ++kf) {
      const int ko = (kf << 5) + (quad << 3);
      const s16x8 a = *(const s16x8*)&Ps[(w << 4) + lr][ko];
#pragma unroll
      for (int j = 0; j < 4; ++j) {
        const s16x8 bb = *(const s16x8*)&Vs[(j << 4) + lr][ko];
        acc[j] = mfma16(a, bb, acc[j]);
      }
    }
  }
#pragma unroll
  for (int j = 0; j < 4; ++j) {
    const int d = (j << 4) + lr;
#pragma unroll
    for (int rr = 0; rr < 4; ++rr) {
      const int q = (w << 4) + (quad << 2) + rr;
      O[(((size_t)bg << 10) + qt0 + q) * 64 + d] = f2bf(acc[j][rr] * lT[q]);
    }
  }
}

// -------- bias2[b][g][o] = bp[o] + bt2[b,g] * sum_d vsum[b,g,d]*wsum[o][d]
__global__ __launch_bounds__(256) void bias2_k(const float* __restrict__ wp,
                                               const float* __restrict__ bp,
                                               const float* __restrict__ ab,
                                               const float* __restrict__ vsum,
                                               float* __restrict__ bias2) {
  const int idx = (blockIdx.x << 8) + threadIdx.x;  // 16384 = B*8*512
  const int b = idx >> 12, g = (idx >> 9) & 7, o = idx & 511;
  const float bt2 = ab[(((b << 3) + g) << 1) + 1];
  const float* wr = wp + (size_t)o * C_;
  const float* vs = vsum + (((b << 3) + g) << 6);
  float acc = 0.f;
#pragma unroll
  for (int d = 0; d < 64; d += 4) {
    const float4 vv4 = *(const float4*)(vs + d);
    float4 ws4 = {0.f, 0.f, 0.f, 0.f};
#pragma unroll
    for (int j = 0; j < 8; ++j) {
      const float4 wv4 = *(const float4*)(wr + (j << 6) + d);
      ws4.x += wv4.x; ws4.y += wv4.y; ws4.z += wv4.z; ws4.w += wv4.w;
    }
    acc += ws4.x * vv4.x + ws4.y * vv4.y + ws4.z * vv4.z + ws4.w * vv4.w;
  }
  bias2[(((b << 3) + g) << 9) + o] = bp[o] + bt2 * acc;
}

// ------- y = al[b,g(t)]*(Mnorm @ Wp^T) + bias2[b][g(t)][o], 64x64 tiles ----
__global__ __launch_bounds__(256) void gemm_proj(const u16* __restrict__ O,
                                                 const float* __restrict__ wp,
                                                 const float* __restrict__ ab,
                                                 const float* __restrict__ bias2,
                                                 float* __restrict__ y) {
  const int b = blockIdx.z;
  const int m0 = blockIdx.y << 6;  // o
  const int n0 = blockIdx.x << 6;  // t
  const int gidx = blockIdx.x >> 1;
  const u16* __restrict__ Ob = O + (size_t)b * (8 * T_ * 64);
  __shared__ u16 As[64][72];
  __shared__ u16 Bs[64][72];
  const int tid = threadIdx.x;
  const int w = tid >> 6, lane = tid & 63, lr = lane & 15, lq = lane >> 4;
  const int mw = (w >> 1) << 5, nw = (w & 1) << 5;
  f32x4 acc[2][2] = {};
  for (int k0 = 0; k0 < C_; k0 += 64) {
#pragma unroll
    for (int it = 0; it < 2; ++it) {
      const int e = tid + (it << 8);
      const int r = e >> 3, c8 = e & 7;
      const float* wr = wp + (size_t)(m0 + r) * C_ + k0 + (c8 << 3);
      const float4 f0 = *(const float4*)wr;
      const float4 f1 = *(const float4*)(wr + 4);
      u16x8 o;
      o[0] = f2bf(f0.x); o[1] = f2bf(f0.y); o[2] = f2bf(f0.z); o[3] = f2bf(f0.w);
      o[4] = f2bf(f1.x); o[5] = f2bf(f1.y); o[6] = f2bf(f1.z); o[7] = f2bf(f1.w);
      *(u16x8*)&As[r][c8 << 3] = o;
      const int t = n0 + r;
      const int c = k0 + (c8 << 3);
      *(u16x8*)&Bs[r][c8 << 3] =
          *(const u16x8*)(Ob + (size_t)(t >> 7) * (T_ * 64) +
                          (size_t)(((t & 127) << 3) + (c >> 6)) * 64 + (c & 63));
    }
    __syncthreads();
#pragma unroll
    for (int kf = 0; kf < 2; ++kf) {
      const int ko = (kf << 5) + (lq << 3);
      s16x8 a[2], bb[2];
#pragma unroll
      for (int i = 0; i < 2; ++i) a[i] = *(const s16x8*)&As[mw + (i << 4) + lr][ko];
#pragma unroll
      for (int j = 0; j < 2; ++j) bb[j] = *(const s16x8*)&Bs[nw + (j << 4) + lr][ko];
#pragma unroll
      for (int i = 0; i < 2; ++i)
#pragma unroll
        for (int j = 0; j < 2; ++j) acc[i][j] = mfma16(a[i], bb[j], acc[i][j]);
    }
    __syncthreads();
  }
  const float al = ab[(((b << 3) + gidx) << 1)];
  const float* __restrict__ b2 = bias2 + (((b << 3) + gidx) << 9);
#pragma unroll
  for (int i = 0; i < 2; ++i) {
    const int row = mw + (i << 4) + (lq << 2);
#pragma unroll
    for (int j = 0; j < 2; ++j) {
      const int col = nw + (j << 4) + lr;
#pragma unroll
      for (int r = 0; r < 4; ++r)
        y[(size_t)b * (C_ * (size_t)T_) + (size_t)(m0 + row + r) * T_ + n0 + col] =
            acc[i][j][r] * al + b2[m0 + row + r];
    }
  }
}

extern "C" void kernel_launch(void* const* d_in, const int* in_sizes, int n_in,
                              void* d_out, int out_size, void* d_ws,
                              size_t ws_size, hipStream_t stream) {
  const float* x = (const float*)d_in[0];
  const float* wq = (const float*)d_in[1];
  const float* wk = (const float*)d_in[2];
  const float* wv = (const float*)d_in[3];
  const float* wh = (const float*)d_in[4];
  const float* gm = (const float*)d_in[5];
  const float* bt = (const float*)d_in[6];
  const float* wp = (const float*)d_in[7];
  const float* bp = (const float*)d_in[8];
  float* y = (float*)d_out;
  char* wsb = (char*)d_ws;

  u16* Qt = (u16*)(wsb + QT_OFF);
  u16* Kt = (u16*)(wsb + KT_OFF);
  u16* V = (u16*)(wsb + V_OFF);
  u16* Xt = (u16*)(wsb + XT_OFF);
  u16* Og = (u16*)(wsb + O_OFF);
  float* ab = (float*)(wsb + AB_OFF);
  float* vsum = (float*)(wsb + VSUM_OFF);
  float* bias2 = (float*)(wsb + BIAS2_OFF);
  u16* P = (u16*)(wsb + P_OFF);
  float* lpart = (float*)(wsb + LP_OFF);
  float* l2part = (float*)(wsb + L2P_OFF);
  float* linv = (float*)(wsb + LINV_OFF);

  transpose_x<<<dim3(16, 8, 4), 256, 0, stream>>>(x, Xt);
  gemm_qkv<<<dim3(16, 8, 12), 256, 0, stream>>>(Xt, wq, wk, wv, Qt, Kt, V);
  vsum_k<<<dim3(32), 256, 0, stream>>>(V, vsum);
  qk_mix<<<dim3(64, 8, 4), 256, 0, stream>>>(Qt, Kt, wh, P, lpart, l2part);
  reduce_l<<<dim3(32), 256, 0, stream>>>(lpart, l2part, gm, bt, linv, ab);
  gemm_pv<<<dim3(16, 32), 256, 0, stream>>>(P, V, linv, Og);
  bias2_k<<<dim3(64), 256, 0, stream>>>(wp, bp, ab, vsum, bias2);
  gemm_proj<<<dim3(16, 8, 4), 256, 0, stream>>>(Og, wp, ab, bias2, y);
}